// Round 9
// baseline (2344.246 us; speedup 1.0000x reference)
//
#include <hip/hip_runtime.h>

typedef float f32x4 __attribute__((ext_vector_type(4)));
typedef float f32x2 __attribute__((ext_vector_type(2)));
typedef short s16x8 __attribute__((ext_vector_type(8)));
typedef __bf16 bf16x8 __attribute__((ext_vector_type(8)));

__device__ __forceinline__ unsigned short f2bf(float f) {
    unsigned int u = __builtin_bit_cast(unsigned int, f);
    u += 0x7FFFu + ((u >> 16) & 1u);
    return (unsigned short)(u >> 16);
}

__device__ __forceinline__ f32x4 MFMA(s16x8 a, s16x8 b, f32x4 c) {
    return __builtin_amdgcn_mfma_f32_16x16x32_bf16(
        __builtin_bit_cast(bf16x8, a), __builtin_bit_cast(bf16x8, b), c, 0, 0, 0);
}

__device__ __forceinline__ float sigm(float v) {
    return __builtin_amdgcn_rcpf(1.f + __builtin_amdgcn_exp2f(-1.4426950408889634f * v));
}
__device__ __forceinline__ float tanh_(float v) {
    return 2.f * __builtin_amdgcn_rcpf(1.f + __builtin_amdgcn_exp2f(-2.8853900817779268f * v)) - 1.f;
}

#define SCHED0 __builtin_amdgcn_sched_barrier(0)

// ---------------- prologue kernels (R5 proven config) ----------------

__global__ void wc_kernel(const float* __restrict__ Wih1, const float* __restrict__ W_enc,
                          const float* __restrict__ b_enc, float* __restrict__ WC,
                          float* __restrict__ benc) {
    int i = blockIdx.x * 256 + threadIdx.x;
    if (i >= 1024 * 35) return;
    int j = i / 35;
    int f = i - j * 35;
    const float* wr = Wih1 + j * 256;
    float s = 0.f;
    if (f < 34) {
        for (int e = 0; e < 256; ++e) s += wr[e] * W_enc[e * 34 + f];
        WC[j * 34 + f] = s;
    } else {
        for (int e = 0; e < 256; ++e) s += wr[e] * b_enc[e];
        benc[j] = s;
    }
}

// Pack W (row-major [srcRows, srcK]) into per-wave-sequential bf16 B-frag streams:
// linear s16x8 index ((ntb*KK + kk)*G + g)*64 + lane holds
//   W[g*gStride + ntb*16 + (lane&15)][kk*32 + (lane>>4)*8 + j]  (0 outside bounds)
__global__ void pack_kernel(const float* __restrict__ src, unsigned short* __restrict__ dst,
                            int NTB, int KK, int G, int gStride, int srcRows, int srcK) {
    int idx = blockIdx.x * 256 + threadIdx.x;
    int total = NTB * KK * G * 64;
    if (idx >= total) return;
    int lane = idx & 63, q = idx >> 6;
    int g = q % G; q /= G;
    int kk = q % KK;
    int ntb = q / KK;
    int row = g * gStride + ntb * 16 + (lane & 15);
    int kbase = kk * 32 + ((lane >> 4) & 3) * 8;
    s16x8 v;
    #pragma unroll
    for (int j = 0; j < 8; ++j) {
        int k = kbase + j;
        float fv = (row < srcRows && k < srcK) ? src[row * srcK + k] : 0.f;
        v[j] = (short)f2bf(fv);
    }
    *(s16x8*)(dst + (long)idx * 8) = v;
}

__global__ void bias_kernel(const float* bih1, const float* bhh1, const float* benc,
                            const float* bih2, const float* bhh2, const float* b_dec,
                            float* bs1a, float* bs1b, float* bs2, float* bdec) {
    int j = blockIdx.x * 256 + threadIdx.x;
    if (j < 1024) {
        float s = bih1[j] + bhh1[j];
        bs1a[j] = s + benc[j];
        bs1b[j] = s;
        bs2[j] = bih2[j] + bhh2[j];
    }
    if (j < 48) bdec[j] = (j < 34) ? b_dec[j] : 0.f;
}

// ---------------- fused LSTM kernel ----------------
//
// A layout (frag-linear, conflict-free): block (u, mt) at
//   base + (u*4 + mt)*520 + lane*8  (shorts); element = Act[mt*16+(l&15)][u*32+(l>>4)*8+j].
//
// R8 structure (B global->register, double-buffered; single barrier/cell) kept.
// R9 change: tile loops FULLY UNROLLED so all operand addresses fold to
// base + compile-time constants (global: one 64-bit add per 4KB tile + offset:
// immediates; DS: one per-lane base + 16-bit offset immediates for the whole
// buffer; h-scatter: one precomputed base + constant offsets). This removes the
// per-tile select/mul/64-bit-add VALU that made the kernel issue-bound
// (R8 counters: VALUBusy 47% + MfmaUtil 40% ~= issue-saturated).

template<bool DO_A, bool DO_W>
__device__ __forceinline__ void tile_op(s16x8 (&a)[4], s16x8 (&bb)[4], f32x4 (&acc)[4][4],
                                        const unsigned short* aNext,
                                        const unsigned short* wNext) {
    #pragma unroll
    for (int mt = 0; mt < 4; ++mt) {
        acc[0][mt] = MFMA(a[mt], bb[0], acc[0][mt]);
        acc[1][mt] = MFMA(a[mt], bb[1], acc[1][mt]);
        acc[2][mt] = MFMA(a[mt], bb[2], acc[2][mt]);
        acc[3][mt] = MFMA(a[mt], bb[3], acc[3][mt]);
        if constexpr (DO_A) a[mt] = *(const s16x8*)(aNext + mt * 520);
        SCHED0;
    }
    if constexpr (DO_W) {
        bb[0] = *(const s16x8*)(wNext);
        bb[1] = *(const s16x8*)(wNext + 512);
        bb[2] = *(const s16x8*)(wNext + 1024);
        bb[3] = *(const s16x8*)(wNext + 1536);
    }
    SCHED0;
}

template<int KKIN>
__device__ __forceinline__ void cell_step(
    const unsigned short* Ain,   // frag-linear (tile u at +u*2080)
    const unsigned short* Ahid,
    const unsigned short* __restrict__ pWin,
    const unsigned short* __restrict__ pWhid,
    const float* Lbias, float (&cst)[2][4][4], unsigned short* Hout,
    int wave, int lane, int ln15, int quad) {
    constexpr int T = KKIN + 8;  // 10 or 16 (even)
    const int wv2 = wave * 2;

    // per-lane stream bases (computed once; all per-tile addressing folds to
    // these + compile-time constants after full unroll)
    const unsigned short* aIn  = Ain  + lane * 8;
    const unsigned short* aHid = Ahid + lane * 8;
    const unsigned short* wInS[2]  = { pWin + wv2 * (KKIN * 2048) + lane * 8,
                                       pWin + (wv2 + 1) * (KKIN * 2048) + lane * 8 };
    const unsigned short* wHidS[2] = { pWhid + wv2 * (8 * 2048) + lane * 8,
                                       pWhid + (wv2 + 1) * (8 * 2048) + lane * 8 };
    const int hbase = wave * 2080 + quad * 32 + (ln15 >> 3) * 128 + (ln15 & 7);

    auto bsrc = [&](int v) -> const unsigned short* {  // v in [0, 2T), compile-time
        int ss = (v >= T) ? 1 : 0;
        int u = v - ss * T;
        return (u < KKIN) ? wInS[ss] + u * 2048 : wHidS[ss] + (u - KKIN) * 2048;
    };
    auto asrc = [&](int v) -> const unsigned short* {  // A independent of stream s
        int u = (v >= T) ? v - T : v;
        return (u < KKIN) ? aIn + u * 2080 : aHid + (u - KKIN) * 2080;
    };

    s16x8 a[4], b0[4], b1[4];
    f32x4 acc[4][4];

    // prologue: W(0)->b0, W(1)->b1 in flight; a = A(0)
    {
        const unsigned short* p0 = bsrc(0);
        const unsigned short* p1 = bsrc(1);
        b0[0] = *(const s16x8*)(p0);
        b0[1] = *(const s16x8*)(p0 + 512);
        b0[2] = *(const s16x8*)(p0 + 1024);
        b0[3] = *(const s16x8*)(p0 + 1536);
        b1[0] = *(const s16x8*)(p1);
        b1[1] = *(const s16x8*)(p1 + 512);
        b1[2] = *(const s16x8*)(p1 + 1024);
        b1[3] = *(const s16x8*)(p1 + 1536);
        const unsigned short* ap = asrc(0);
        #pragma unroll
        for (int mt = 0; mt < 4; ++mt)
            a[mt] = *(const s16x8*)(ap + mt * 520);
    }

    #pragma unroll
    for (int s = 0; s < 2; ++s) {
        #pragma unroll
        for (int g = 0; g < 4; ++g)
            #pragma unroll
            for (int mt = 0; mt < 4; ++mt) acc[g][mt] = f32x4{0.f, 0.f, 0.f, 0.f};
        constexpr int nrm0 = T;        // s=0: full stream (prefetch crosses into s=1)
        constexpr int nrm1 = T - 2;    // s=1: last pair peeled (drain)
        const int nrm = s ? nrm1 : nrm0;
        #pragma unroll
        for (int u = 0; u < nrm; u += 2) {
            const int v = s * T + u;  // compile-time after unroll
            tile_op<true, true>(a, b0, acc, asrc(v + 1), bsrc(v + 2));
            tile_op<true, true>(a, b1, acc, asrc(v + 2), bsrc(v + 3));
        }
        if (s == 1) {
            tile_op<true, false>(a, b0, acc, asrc(2 * T - 1), nullptr);
            tile_op<false, false>(a, b1, acc, nullptr, nullptr);
        }

        // epilogue for column-stream s: gates -> c,h; h written inline (Hout is
        // the parity buffer nobody reads this step). Scatter offsets all constant.
        const int colB = (wv2 + s) * 16 + ln15;
        const float bi = Lbias[colB], bff = Lbias[256 + colB];
        const float bg = Lbias[512 + colB], bo = Lbias[768 + colB];
        #pragma unroll
        for (int mt = 0; mt < 4; ++mt) {
            #pragma unroll
            for (int r = 0; r < 4; ++r) {
                float iv = acc[0][mt][r] + bi;
                float fv = acc[1][mt][r] + bff;
                float gv = acc[2][mt][r] + bg;
                float ov = acc[3][mt][r] + bo;
                float cn = sigm(fv) * cst[s][mt][r] + sigm(iv) * tanh_(gv);
                cst[s][mt][r] = cn;
                float hv = sigm(ov) * tanh_(cn);
                Hout[hbase + mt * 520 + r * 8 + s * 256] = f2bf(hv);
            }
        }
    }
    __syncthreads();  // publish new h (single barrier per cell)
}

// LDS: h1f[2] + h2f[2] (4 x 33280) + scratch 12288 + Lb 12288 + Lbd 256 = 157952 B.
__global__ __launch_bounds__(512, 1) void lstm_fused(
    const float* __restrict__ x,
    const unsigned short* __restrict__ pWC,
    const unsigned short* __restrict__ pWih1,
    const unsigned short* __restrict__ pWhh1,
    const unsigned short* __restrict__ pWih2,
    const unsigned short* __restrict__ pWhh2,
    const unsigned short* __restrict__ pWdec,
    const float* __restrict__ gb1a, const float* __restrict__ gb1b,
    const float* __restrict__ gb2, const float* __restrict__ gbd,
    float* __restrict__ out) {
    extern __shared__ unsigned char smem[];
    unsigned short* h1lo = (unsigned short*)smem;                 // 16640 shorts each
    unsigned short* h1hi = h1lo + 16640;
    unsigned short* h2lo = h1hi + 16640;
    unsigned short* h2hi = h2lo + 16640;
    unsigned char* scratch = (unsigned char*)(h2hi + 16640);      // 12288 B union:
    unsigned short* xfrag = (unsigned short*)scratch;             //   obs: 2u x 4mt x 520
    float* dOut = (float*)scratch;                                //   dec: 64 x 48 f32
    float* Lb1a = (float*)(scratch + 12288);
    float* Lb1b = Lb1a + 1024;
    float* Lb2  = Lb1b + 1024;
    float* Lbd  = Lb2 + 1024;                                     // 48 used (256 B)

    const int tid = threadIdx.x;
    const int wave = tid >> 6;
    const int lane = tid & 63;
    const int ln15 = lane & 15;
    const int quad = lane >> 4;
    const int m0 = blockIdx.x * 64;

    for (int i = tid; i < 33280; i += 512) ((int*)h1lo)[i] = 0;   // all 4 h buffers
    for (int i = tid; i < 3072; i += 512) ((int*)scratch)[i] = 0;
    for (int i = tid; i < 1024; i += 512) { Lb1a[i] = gb1a[i]; Lb1b[i] = gb1b[i]; Lb2[i] = gb2[i]; }
    if (tid < 48) Lbd[tid] = gbd[tid];

    float c1[2][4][4], c2[2][4][4];
    #pragma unroll
    for (int s = 0; s < 2; ++s)
        #pragma unroll
        for (int mt = 0; mt < 4; ++mt)
            #pragma unroll
            for (int r = 0; r < 4; ++r) { c1[s][mt][r] = 0.f; c2[s][mt][r] = 0.f; }

    __syncthreads();

    #pragma unroll 1
    for (int t = 0; t < 19; ++t) {
        const int cur = t & 1;
        unsigned short* h1r = cur ? h1hi : h1lo;
        unsigned short* h1w = cur ? h1lo : h1hi;
        unsigned short* h2r = cur ? h2hi : h2lo;
        unsigned short* h2w = cur ? h2lo : h2hi;

        if (t < 10) {
            // stage x_t -> xfrag (bf16, fragment-linear; chunks for cols 34..63 stay zero)
            for (int i = tid; i < 1088; i += 512) {
                int r = i / 17, p = i - r * 17;
                int c = 2 * p;
                f32x2 v = __builtin_nontemporal_load((const f32x2*)(x + (m0 + r) * 340 + t * 34) + p);
                int u = c >> 5, mt = r >> 4;
                int laneA = (r & 15) | (((c >> 3) & 3) << 4);
                unsigned int packed = (unsigned int)f2bf(v.x) | ((unsigned int)f2bf(v.y) << 16);
                *(unsigned int*)(xfrag + (u * 4 + mt) * 520 + laneA * 8 + (c & 7)) = packed;
            }
            __syncthreads();
            cell_step<2>(xfrag, h1r, pWC, pWhh1, Lb1a, c1, h1w, wave, lane, ln15, quad);
        } else {
            cell_step<8>(h2r, h1r, pWih1, pWhh1, Lb1b, c1, h1w, wave, lane, ln15, quad);
        }
        cell_step<8>(h1w, h2r, pWih2, pWhh2, Lb2, c2, h2w, wave, lane, ln15, quad);

        if (t >= 9) {
            const int tout = t - 9;
            if (wave < 3) {  // decoder: dec = h2 @ W_dec^T + b_dec ; cumsum in dOut (LDS)
                f32x4 d[4];
                #pragma unroll
                for (int mt = 0; mt < 4; ++mt) d[mt] = f32x4{0.f, 0.f, 0.f, 0.f};
                const unsigned short* hb = h2w + lane * 8;
                const unsigned short* wb = pWdec + (wave * 8) * 512 + lane * 8;
                #pragma unroll
                for (int kk = 0; kk < 8; ++kk) {
                    s16x8 b = *(const s16x8*)(wb + kk * 512);
                    #pragma unroll
                    for (int mt = 0; mt < 4; ++mt) {
                        s16x8 a = *(const s16x8*)(hb + (kk * 4 + mt) * 520);
                        d[mt] = MFMA(a, b, d[mt]);
                    }
                }
                const int col = wave * 16 + ln15;
                const bool valid = (col < 34);
                const float bd = Lbd[col];
                #pragma unroll
                for (int mt = 0; mt < 4; ++mt) {
                    #pragma unroll
                    for (int r = 0; r < 4; ++r) {
                        const int rloc = mt * 16 + quad * 4 + r;
                        float v = d[mt][r] + bd;
                        if (tout == 0) {
                            float xr = valid ? __builtin_nontemporal_load(x + (m0 + rloc) * 340 + 306 + col) : 0.f;
                            dOut[rloc * 48 + col] = v + xr;
                        } else {
                            dOut[rloc * 48 + col] += v;
                        }
                    }
                }
            }
            __syncthreads();
            // contiguous per-row non-temporal stores
            for (int i = tid; i < 1088; i += 512) {
                int r = i / 17, p = i - r * 17;
                f32x2 v = *(const f32x2*)(dOut + r * 48 + p * 2);
                __builtin_nontemporal_store(v, (f32x2*)(out + (m0 + r) * 340 + tout * 34) + p);
            }
            // safe: staging only at t<10, decoder rewrite of dOut only after 2 cell barriers
        }
    }
}

// ---------------- launch ----------------

extern "C" void kernel_launch(void* const* d_in, const int* in_sizes, int n_in,
                              void* d_out, int out_size, void* d_ws, size_t ws_size,
                              hipStream_t stream) {
    const float* x     = (const float*)d_in[0];
    const float* W_enc = (const float*)d_in[1];
    const float* b_enc = (const float*)d_in[2];
    const float* Wih1  = (const float*)d_in[3];
    const float* Whh1  = (const float*)d_in[4];
    const float* bih1  = (const float*)d_in[5];
    const float* bhh1  = (const float*)d_in[6];
    const float* Wih2  = (const float*)d_in[7];
    const float* Whh2  = (const float*)d_in[8];
    const float* bih2  = (const float*)d_in[9];
    const float* bhh2  = (const float*)d_in[10];
    const float* W_dec = (const float*)d_in[11];
    const float* b_dec = (const float*)d_in[12];
    float* out = (float*)d_out;

    unsigned char* w = (unsigned char*)d_ws;
    float* WC   = (float*)(w + 0);         // 139264
    float* benc = (float*)(w + 139264);    // 4096
    float* bs1a = (float*)(w + 143360);
    float* bs1b = (float*)(w + 147456);
    float* bs2  = (float*)(w + 151552);
    float* bdec = (float*)(w + 155648);    // 256
    unsigned short* pWC   = (unsigned short*)(w + 155904);   // 131072
    unsigned short* pWih1 = (unsigned short*)(w + 286976);   // 524288 each
    unsigned short* pWhh1 = (unsigned short*)(w + 811264);
    unsigned short* pWih2 = (unsigned short*)(w + 1335552);
    unsigned short* pWhh2 = (unsigned short*)(w + 1859840);
    unsigned short* pWdec = (unsigned short*)(w + 2384128);  // 24576

    wc_kernel<<<140, 256, 0, stream>>>(Wih1, W_enc, b_enc, WC, benc);
    pack_kernel<<<32, 256, 0, stream>>>(WC, pWC, 16, 2, 4, 256, 1024, 34);
    pack_kernel<<<128, 256, 0, stream>>>(Wih1, pWih1, 16, 8, 4, 256, 1024, 256);
    pack_kernel<<<128, 256, 0, stream>>>(Whh1, pWhh1, 16, 8, 4, 256, 1024, 256);
    pack_kernel<<<128, 256, 0, stream>>>(Wih2, pWih2, 16, 8, 4, 256, 1024, 256);
    pack_kernel<<<128, 256, 0, stream>>>(Whh2, pWhh2, 16, 8, 4, 256, 1024, 256);
    pack_kernel<<<6, 256, 0, stream>>>(W_dec, pWdec, 3, 8, 1, 0, 34, 256);
    bias_kernel<<<4, 256, 0, stream>>>(bih1, bhh1, benc, bih2, bhh2, b_dec, bs1a, bs1b, bs2, bdec);

    hipFuncSetAttribute((const void*)lstm_fused, hipFuncAttributeMaxDynamicSharedMemorySize, 157952);
    lstm_fused<<<256, 512, 157952, stream>>>(x, pWC, pWih1, pWhh1, pWih2, pWhh2, pWdec,
                                             bs1a, bs1b, bs2, bdec, out);
}

// Round 10
// 747.282 us; speedup vs baseline: 3.1370x; 3.1370x over previous
//
#include <hip/hip_runtime.h>

typedef float f32x4 __attribute__((ext_vector_type(4)));
typedef float f32x2 __attribute__((ext_vector_type(2)));
typedef short s16x8 __attribute__((ext_vector_type(8)));
typedef __bf16 bf16x8 __attribute__((ext_vector_type(8)));

__device__ __forceinline__ unsigned short f2bf(float f) {
    unsigned int u = __builtin_bit_cast(unsigned int, f);
    u += 0x7FFFu + ((u >> 16) & 1u);
    return (unsigned short)(u >> 16);
}

__device__ __forceinline__ f32x4 MFMA(s16x8 a, s16x8 b, f32x4 c) {
    return __builtin_amdgcn_mfma_f32_16x16x32_bf16(
        __builtin_bit_cast(bf16x8, a), __builtin_bit_cast(bf16x8, b), c, 0, 0, 0);
}

__device__ __forceinline__ float sigm(float v) {
    return __builtin_amdgcn_rcpf(1.f + __builtin_amdgcn_exp2f(-1.4426950408889634f * v));
}
__device__ __forceinline__ float tanh_(float v) {
    return 2.f * __builtin_amdgcn_rcpf(1.f + __builtin_amdgcn_exp2f(-2.8853900817779268f * v)) - 1.f;
}

#define SCHED0 __builtin_amdgcn_sched_barrier(0)

// ---------------- prologue kernels (R5 proven config) ----------------

__global__ void wc_kernel(const float* __restrict__ Wih1, const float* __restrict__ W_enc,
                          const float* __restrict__ b_enc, float* __restrict__ WC,
                          float* __restrict__ benc) {
    int i = blockIdx.x * 256 + threadIdx.x;
    if (i >= 1024 * 35) return;
    int j = i / 35;
    int f = i - j * 35;
    const float* wr = Wih1 + j * 256;
    float s = 0.f;
    if (f < 34) {
        for (int e = 0; e < 256; ++e) s += wr[e] * W_enc[e * 34 + f];
        WC[j * 34 + f] = s;
    } else {
        for (int e = 0; e < 256; ++e) s += wr[e] * b_enc[e];
        benc[j] = s;
    }
}

// Pack W (row-major [srcRows, srcK]) into per-wave-sequential bf16 B-frag streams:
// linear s16x8 index ((ntb*KK + kk)*G + g)*64 + lane holds
//   W[g*gStride + ntb*16 + (lane&15)][kk*32 + (lane>>4)*8 + j]  (0 outside bounds)
__global__ void pack_kernel(const float* __restrict__ src, unsigned short* __restrict__ dst,
                            int NTB, int KK, int G, int gStride, int srcRows, int srcK) {
    int idx = blockIdx.x * 256 + threadIdx.x;
    int total = NTB * KK * G * 64;
    if (idx >= total) return;
    int lane = idx & 63, q = idx >> 6;
    int g = q % G; q /= G;
    int kk = q % KK;
    int ntb = q / KK;
    int row = g * gStride + ntb * 16 + (lane & 15);
    int kbase = kk * 32 + ((lane >> 4) & 3) * 8;
    s16x8 v;
    #pragma unroll
    for (int j = 0; j < 8; ++j) {
        int k = kbase + j;
        float fv = (row < srcRows && k < srcK) ? src[row * srcK + k] : 0.f;
        v[j] = (short)f2bf(fv);
    }
    *(s16x8*)(dst + (long)idx * 8) = v;
}

__global__ void bias_kernel(const float* bih1, const float* bhh1, const float* benc,
                            const float* bih2, const float* bhh2, const float* b_dec,
                            float* bs1a, float* bs1b, float* bs2, float* bdec) {
    int j = blockIdx.x * 256 + threadIdx.x;
    if (j < 1024) {
        float s = bih1[j] + bhh1[j];
        bs1a[j] = s + benc[j];
        bs1b[j] = s;
        bs2[j] = bih2[j] + bhh2[j];
    }
    if (j < 48) bdec[j] = (j < 34) ? b_dec[j] : 0.f;
}

// ---------------- fused LSTM kernel ----------------
//
// A layout (frag-linear, conflict-free): block (u, mt) at
//   base + (u*4 + mt)*520 + lane*8  (shorts); element = Act[mt*16+(l&15)][u*32+(l>>4)*8+j].
//
// R8 structure kept EXACTLY (B global->register double-buffer, mt-outer tile
// order, single barrier/cell, #pragma unroll 1 on the pair loop -- R9 proved the
// unroll-1 is load-bearing: full unroll let the scheduler rename/hoist loads and
// spill catastrophically).
// R10 deltas (surgical):
//  1. cross-cell B preload: drain tiles reload b0/b1 with the NEXT cell's
//     W(0)/W(1) (same registers). The cell-ending __syncthreads' vmcnt(0) drain
//     forces them complete -> their L2 latency hides under the epilogue VALU,
//     and the next cell starts MFMAs immediately (removes per-cell cold start).
//     b0/b1 are kernel-scope and preloaded once before the t-loop.
//  2. lane*8 hoisted into all stream bases; h-scatter base precomputed
//     (pure VALU trim, no structural change).

template<bool DO_A, bool DO_W>
__device__ __forceinline__ void tile_op(s16x8 (&a)[4], s16x8 (&bb)[4], f32x4 (&acc)[4][4],
                                        const unsigned short* aNext,
                                        const unsigned short* wNext) {
    #pragma unroll
    for (int mt = 0; mt < 4; ++mt) {
        acc[0][mt] = MFMA(a[mt], bb[0], acc[0][mt]);
        acc[1][mt] = MFMA(a[mt], bb[1], acc[1][mt]);
        acc[2][mt] = MFMA(a[mt], bb[2], acc[2][mt]);
        acc[3][mt] = MFMA(a[mt], bb[3], acc[3][mt]);
        if constexpr (DO_A) a[mt] = *(const s16x8*)(aNext + mt * 520);
        SCHED0;
    }
    if constexpr (DO_W) {
        bb[0] = *(const s16x8*)(wNext);
        bb[1] = *(const s16x8*)(wNext + 512);
        bb[2] = *(const s16x8*)(wNext + 1024);
        bb[3] = *(const s16x8*)(wNext + 1536);
    }
    SCHED0;
}

template<int KKIN>
__device__ __forceinline__ void cell_step(
    const unsigned short* Ain,   // frag-linear (tile u at +u*2080), not lane-adjusted
    const unsigned short* Ahid,
    const unsigned short* __restrict__ pWin,
    const unsigned short* __restrict__ pWhid,
    const unsigned short* nextW,  // lane-adjusted base of next cell's W(0) for this wave
    const float* Lbias, float (&cst)[2][4][4], unsigned short* Hout,
    s16x8 (&b0)[4], s16x8 (&b1)[4],
    int wave, int lane, int ln15, int quad) {
    constexpr int T = KKIN + 8;  // 10 or 16 (even)
    const int wv2 = wave * 2;

    // per-lane stream bases (computed once)
    const unsigned short* aInL  = Ain  + lane * 8;
    const unsigned short* aHidL = Ahid + lane * 8;
    const unsigned short* wIn0  = pWin  + wv2 * (KKIN * 2048) + lane * 8;
    const unsigned short* wIn1  = pWin  + (wv2 + 1) * (KKIN * 2048) + lane * 8;
    const unsigned short* wHid0 = pWhid + wv2 * (8 * 2048) + lane * 8;
    const unsigned short* wHid1 = pWhid + (wv2 + 1) * (8 * 2048) + lane * 8;
    const int hbase = wave * 2080 + quad * 32 + (ln15 >> 3) * 128 + (ln15 & 7);

    auto bsrc = [&](int v) -> const unsigned short* {  // v in [2, 2T)
        int ss = (v >= T) ? 1 : 0;
        int u = v - ss * T;
        const unsigned short* wi = ss ? wIn1 : wIn0;
        const unsigned short* wh = ss ? wHid1 : wHid0;
        return (u < KKIN) ? wi + u * 2048 : wh + (u - KKIN) * 2048;
    };
    auto asrc = [&](int v) -> const unsigned short* {  // A independent of stream s
        int u = (v >= T) ? v - T : v;
        return (u < KKIN) ? aInL + u * 2080 : aHidL + (u - KKIN) * 2080;
    };

    s16x8 a[4];
    f32x4 acc[4][4];

    // prologue: b0/b1 already hold W(0)/W(1) (preloaded by the previous cell's
    // drain tiles, forced complete by the barrier). Only A(0) to fetch.
    {
        const unsigned short* ap = asrc(0);
        #pragma unroll
        for (int mt = 0; mt < 4; ++mt)
            a[mt] = *(const s16x8*)(ap + mt * 520);
    }

    #pragma unroll
    for (int s = 0; s < 2; ++s) {
        #pragma unroll
        for (int g = 0; g < 4; ++g)
            #pragma unroll
            for (int mt = 0; mt < 4; ++mt) acc[g][mt] = f32x4{0.f, 0.f, 0.f, 0.f};
        const int nrm = s ? (T - 2) : T;  // s=1: last pair peeled (next-cell preload)
        #pragma unroll 1
        for (int u = 0; u < nrm; u += 2) {
            const int v = s * T + u;  // even
            tile_op<true, true>(a, b0, acc, asrc(v + 1), bsrc(v + 2));
            tile_op<true, true>(a, b1, acc, asrc(v + 2), bsrc(v + 3));
        }
        if (s == 1) {
            // drain tiles: consume b0/b1, refill them with NEXT cell's W(0)/W(1)
            tile_op<true, true>(a, b0, acc, asrc(2 * T - 1), nextW);
            tile_op<false, true>(a, b1, acc, nullptr, nextW + 2048);
        }

        // epilogue for column-stream s: gates -> c,h; h written inline (Hout is
        // the parity buffer nobody reads this step). Scatter offsets constant.
        const int colB = (wv2 + s) * 16 + ln15;
        const float bi = Lbias[colB], bff = Lbias[256 + colB];
        const float bg = Lbias[512 + colB], bo = Lbias[768 + colB];
        #pragma unroll
        for (int mt = 0; mt < 4; ++mt) {
            #pragma unroll
            for (int r = 0; r < 4; ++r) {
                float iv = acc[0][mt][r] + bi;
                float fv = acc[1][mt][r] + bff;
                float gv = acc[2][mt][r] + bg;
                float ov = acc[3][mt][r] + bo;
                float cn = sigm(fv) * cst[s][mt][r] + sigm(iv) * tanh_(gv);
                cst[s][mt][r] = cn;
                float hv = sigm(ov) * tanh_(cn);
                Hout[hbase + mt * 520 + r * 8 + s * 256] = f2bf(hv);
            }
        }
    }
    __syncthreads();  // publish new h; vmcnt(0) drain completes the preloaded b0/b1
}

// LDS: h1f[2] + h2f[2] (4 x 33280) + scratch 12288 + Lb 12288 + Lbd 256 = 157952 B.
__global__ __launch_bounds__(512, 1) void lstm_fused(
    const float* __restrict__ x,
    const unsigned short* __restrict__ pWC,
    const unsigned short* __restrict__ pWih1,
    const unsigned short* __restrict__ pWhh1,
    const unsigned short* __restrict__ pWih2,
    const unsigned short* __restrict__ pWhh2,
    const unsigned short* __restrict__ pWdec,
    const float* __restrict__ gb1a, const float* __restrict__ gb1b,
    const float* __restrict__ gb2, const float* __restrict__ gbd,
    float* __restrict__ out) {
    extern __shared__ unsigned char smem[];
    unsigned short* h1lo = (unsigned short*)smem;                 // 16640 shorts each
    unsigned short* h1hi = h1lo + 16640;
    unsigned short* h2lo = h1hi + 16640;
    unsigned short* h2hi = h2lo + 16640;
    unsigned char* scratch = (unsigned char*)(h2hi + 16640);      // 12288 B union:
    unsigned short* xfrag = (unsigned short*)scratch;             //   obs: 2u x 4mt x 520
    float* dOut = (float*)scratch;                                //   dec: 64 x 48 f32
    float* Lb1a = (float*)(scratch + 12288);
    float* Lb1b = Lb1a + 1024;
    float* Lb2  = Lb1b + 1024;
    float* Lbd  = Lb2 + 1024;                                     // 48 used (256 B)

    const int tid = threadIdx.x;
    const int wave = tid >> 6;
    const int lane = tid & 63;
    const int ln15 = lane & 15;
    const int quad = lane >> 4;
    const int m0 = blockIdx.x * 64;

    // per-wave, lane-adjusted first-W bases for cross-cell preload
    const unsigned short* nbWC   = pWC   + wave * 2 * (2 * 2048) + lane * 8;
    const unsigned short* nbWih1 = pWih1 + wave * 2 * (8 * 2048) + lane * 8;
    const unsigned short* nbWih2 = pWih2 + wave * 2 * (8 * 2048) + lane * 8;

    // kernel-scope B double-buffer; preload first cell's W(0)/W(1) (pWC stream)
    s16x8 b0[4], b1[4];
    b0[0] = *(const s16x8*)(nbWC);
    b0[1] = *(const s16x8*)(nbWC + 512);
    b0[2] = *(const s16x8*)(nbWC + 1024);
    b0[3] = *(const s16x8*)(nbWC + 1536);
    b1[0] = *(const s16x8*)(nbWC + 2048);
    b1[1] = *(const s16x8*)(nbWC + 2560);
    b1[2] = *(const s16x8*)(nbWC + 3072);
    b1[3] = *(const s16x8*)(nbWC + 3584);

    for (int i = tid; i < 33280; i += 512) ((int*)h1lo)[i] = 0;   // all 4 h buffers
    for (int i = tid; i < 3072; i += 512) ((int*)scratch)[i] = 0;
    for (int i = tid; i < 1024; i += 512) { Lb1a[i] = gb1a[i]; Lb1b[i] = gb1b[i]; Lb2[i] = gb2[i]; }
    if (tid < 48) Lbd[tid] = gbd[tid];

    float c1[2][4][4], c2[2][4][4];
    #pragma unroll
    for (int s = 0; s < 2; ++s)
        #pragma unroll
        for (int mt = 0; mt < 4; ++mt)
            #pragma unroll
            for (int r = 0; r < 4; ++r) { c1[s][mt][r] = 0.f; c2[s][mt][r] = 0.f; }

    __syncthreads();

    #pragma unroll 1
    for (int t = 0; t < 19; ++t) {
        const int cur = t & 1;
        unsigned short* h1r = cur ? h1hi : h1lo;
        unsigned short* h1w = cur ? h1lo : h1hi;
        unsigned short* h2r = cur ? h2hi : h2lo;
        unsigned short* h2w = cur ? h2lo : h2hi;
        // cell1's successor is cell2 (pWih2); cell2's successor is next t's cell1
        const unsigned short* nAfter2 = (t + 1 < 10) ? nbWC : nbWih1;  // t=18: dummy-read, unused

        if (t < 10) {
            // stage x_t -> xfrag (bf16, fragment-linear; chunks for cols 34..63 stay zero)
            for (int i = tid; i < 1088; i += 512) {
                int r = i / 17, p = i - r * 17;
                int c = 2 * p;
                f32x2 v = __builtin_nontemporal_load((const f32x2*)(x + (m0 + r) * 340 + t * 34) + p);
                int u = c >> 5, mt = r >> 4;
                int laneA = (r & 15) | (((c >> 3) & 3) << 4);
                unsigned int packed = (unsigned int)f2bf(v.x) | ((unsigned int)f2bf(v.y) << 16);
                *(unsigned int*)(xfrag + (u * 4 + mt) * 520 + laneA * 8 + (c & 7)) = packed;
            }
            __syncthreads();
            cell_step<2>(xfrag, h1r, pWC, pWhh1, nbWih2, Lb1a, c1, h1w, b0, b1, wave, lane, ln15, quad);
        } else {
            cell_step<8>(h2r, h1r, pWih1, pWhh1, nbWih2, Lb1b, c1, h1w, b0, b1, wave, lane, ln15, quad);
        }
        cell_step<8>(h1w, h2r, pWih2, pWhh2, nAfter2, Lb2, c2, h2w, b0, b1, wave, lane, ln15, quad);

        if (t >= 9) {
            const int tout = t - 9;
            if (wave < 3) {  // decoder: dec = h2 @ W_dec^T + b_dec ; cumsum in dOut (LDS)
                f32x4 d[4];
                #pragma unroll
                for (int mt = 0; mt < 4; ++mt) d[mt] = f32x4{0.f, 0.f, 0.f, 0.f};
                const unsigned short* hb = h2w + lane * 8;
                const unsigned short* wb = pWdec + (wave * 8) * 512 + lane * 8;
                #pragma unroll
                for (int kk = 0; kk < 8; ++kk) {
                    s16x8 b = *(const s16x8*)(wb + kk * 512);
                    #pragma unroll
                    for (int mt = 0; mt < 4; ++mt) {
                        s16x8 a = *(const s16x8*)(hb + (kk * 4 + mt) * 520);
                        d[mt] = MFMA(a, b, d[mt]);
                    }
                }
                const int col = wave * 16 + ln15;
                const bool valid = (col < 34);
                const float bd = Lbd[col];
                #pragma unroll
                for (int mt = 0; mt < 4; ++mt) {
                    #pragma unroll
                    for (int r = 0; r < 4; ++r) {
                        const int rloc = mt * 16 + quad * 4 + r;
                        float v = d[mt][r] + bd;
                        if (tout == 0) {
                            float xr = valid ? __builtin_nontemporal_load(x + (m0 + rloc) * 340 + 306 + col) : 0.f;
                            dOut[rloc * 48 + col] = v + xr;
                        } else {
                            dOut[rloc * 48 + col] += v;
                        }
                    }
                }
            }
            __syncthreads();
            // contiguous per-row non-temporal stores
            for (int i = tid; i < 1088; i += 512) {
                int r = i / 17, p = i - r * 17;
                f32x2 v = *(const f32x2*)(dOut + r * 48 + p * 2);
                __builtin_nontemporal_store(v, (f32x2*)(out + (m0 + r) * 340 + tout * 34) + p);
            }
            // safe: staging only at t<10, decoder rewrite of dOut only after 2 cell barriers
        }
    }
}

// ---------------- launch ----------------

extern "C" void kernel_launch(void* const* d_in, const int* in_sizes, int n_in,
                              void* d_out, int out_size, void* d_ws, size_t ws_size,
                              hipStream_t stream) {
    const float* x     = (const float*)d_in[0];
    const float* W_enc = (const float*)d_in[1];
    const float* b_enc = (const float*)d_in[2];
    const float* Wih1  = (const float*)d_in[3];
    const float* Whh1  = (const float*)d_in[4];
    const float* bih1  = (const float*)d_in[5];
    const float* bhh1  = (const float*)d_in[6];
    const float* Wih2  = (const float*)d_in[7];
    const float* Whh2  = (const float*)d_in[8];
    const float* bih2  = (const float*)d_in[9];
    const float* bhh2  = (const float*)d_in[10];
    const float* W_dec = (const float*)d_in[11];
    const float* b_dec = (const float*)d_in[12];
    float* out = (float*)d_out;

    unsigned char* w = (unsigned char*)d_ws;
    float* WC   = (float*)(w + 0);         // 139264
    float* benc = (float*)(w + 139264);    // 4096
    float* bs1a = (float*)(w + 143360);
    float* bs1b = (float*)(w + 147456);
    float* bs2  = (float*)(w + 151552);
    float* bdec = (float*)(w + 155648);    // 256
    unsigned short* pWC   = (unsigned short*)(w + 155904);   // 131072
    unsigned short* pWih1 = (unsigned short*)(w + 286976);   // 524288 each
    unsigned short* pWhh1 = (unsigned short*)(w + 811264);
    unsigned short* pWih2 = (unsigned short*)(w + 1335552);
    unsigned short* pWhh2 = (unsigned short*)(w + 1859840);
    unsigned short* pWdec = (unsigned short*)(w + 2384128);  // 24576

    wc_kernel<<<140, 256, 0, stream>>>(Wih1, W_enc, b_enc, WC, benc);
    pack_kernel<<<32, 256, 0, stream>>>(WC, pWC, 16, 2, 4, 256, 1024, 34);
    pack_kernel<<<128, 256, 0, stream>>>(Wih1, pWih1, 16, 8, 4, 256, 1024, 256);
    pack_kernel<<<128, 256, 0, stream>>>(Whh1, pWhh1, 16, 8, 4, 256, 1024, 256);
    pack_kernel<<<128, 256, 0, stream>>>(Wih2, pWih2, 16, 8, 4, 256, 1024, 256);
    pack_kernel<<<128, 256, 0, stream>>>(Whh2, pWhh2, 16, 8, 4, 256, 1024, 256);
    pack_kernel<<<6, 256, 0, stream>>>(W_dec, pWdec, 3, 8, 1, 0, 34, 256);
    bias_kernel<<<4, 256, 0, stream>>>(bih1, bhh1, benc, bih2, bhh2, b_dec, bs1a, bs1b, bs2, bdec);

    hipFuncSetAttribute((const void*)lstm_fused, hipFuncAttributeMaxDynamicSharedMemorySize, 157952);
    lstm_fused<<<256, 512, 157952, stream>>>(x, pWC, pWih1, pWhh1, pWih2, pWhh2, pWdec,
                                             bs1a, bs1b, bs2, bdec, out);
}

// Round 11
// 680.022 us; speedup vs baseline: 3.4473x; 1.0989x over previous
//
#include <hip/hip_runtime.h>

typedef float f32x4 __attribute__((ext_vector_type(4)));
typedef float f32x2 __attribute__((ext_vector_type(2)));
typedef short s16x8 __attribute__((ext_vector_type(8)));
typedef __bf16 bf16x8 __attribute__((ext_vector_type(8)));

__device__ __forceinline__ unsigned short f2bf(float f) {
    unsigned int u = __builtin_bit_cast(unsigned int, f);
    u += 0x7FFFu + ((u >> 16) & 1u);
    return (unsigned short)(u >> 16);
}

__device__ __forceinline__ f32x4 MFMA(s16x8 a, s16x8 b, f32x4 c) {
    return __builtin_amdgcn_mfma_f32_16x16x32_bf16(
        __builtin_bit_cast(bf16x8, a), __builtin_bit_cast(bf16x8, b), c, 0, 0, 0);
}

__device__ __forceinline__ float sigm(float v) {
    return __builtin_amdgcn_rcpf(1.f + __builtin_amdgcn_exp2f(-1.4426950408889634f * v));
}
__device__ __forceinline__ float tanh_(float v) {
    return 2.f * __builtin_amdgcn_rcpf(1.f + __builtin_amdgcn_exp2f(-2.8853900817779268f * v)) - 1.f;
}

#define SCHED0 __builtin_amdgcn_sched_barrier(0)

// ---------------- prologue kernels ----------------

__global__ void wc_kernel(const float* __restrict__ Wih1, const float* __restrict__ W_enc,
                          const float* __restrict__ b_enc, float* __restrict__ WC,
                          float* __restrict__ benc) {
    int i = blockIdx.x * 256 + threadIdx.x;
    if (i >= 1024 * 35) return;
    int j = i / 35;
    int f = i - j * 35;
    const float* wr = Wih1 + j * 256;
    float s = 0.f;
    if (f < 34) {
        for (int e = 0; e < 256; ++e) s += wr[e] * W_enc[e * 34 + f];
        WC[j * 34 + f] = s;
    } else {
        for (int e = 0; e < 256; ++e) s += wr[e] * b_enc[e];
        benc[j] = s;
    }
}

// Pack W (row-major [srcRows, srcK]) into per-wave-sequential bf16 B-frag streams:
// linear s16x8 index ((ntb*KK + kk)*G + g)*64 + lane holds
//   W[g*gStride + ntb*16 + (lane&15)][kk*32 + (lane>>4)*8 + j]  (0 outside bounds)
__device__ __forceinline__ void pack_range(const float* __restrict__ src,
                                           unsigned short* __restrict__ dst,
                                           int idx, int KK, int G, int gStride,
                                           int srcRows, int srcK) {
    int lane = idx & 63, q = idx >> 6;
    int g = q % G; q /= G;
    int kk = q % KK;
    int ntb = q / KK;
    int row = g * gStride + ntb * 16 + (lane & 15);
    int kbase = kk * 32 + ((lane >> 4) & 3) * 8;
    s16x8 v;
    #pragma unroll
    for (int j = 0; j < 8; ++j) {
        int k = kbase + j;
        float fv = (row < srcRows && k < srcK) ? src[row * srcK + k] : 0.f;
        v[j] = (short)f2bf(fv);
    }
    *(s16x8*)(dst + (long)idx * 8) = v;
}

// One dispatcher launch replaces the 6 independent pack launches + bias launch.
// Same per-thread work as the individual kernels (NOT R7's on-the-fly WC recompute,
// which was that round's regression); the five half-GPU pack grids now run
// concurrently instead of serialized across launches.
__global__ void prep2_kernel(const float* __restrict__ WC, const float* __restrict__ benc,
                             const float* __restrict__ Wih1, const float* __restrict__ Whh1,
                             const float* __restrict__ Wih2, const float* __restrict__ Whh2,
                             const float* __restrict__ W_dec,
                             const float* __restrict__ bih1, const float* __restrict__ bhh1,
                             const float* __restrict__ bih2, const float* __restrict__ bhh2,
                             const float* __restrict__ b_dec,
                             unsigned short* __restrict__ pWC, unsigned short* __restrict__ pWih1,
                             unsigned short* __restrict__ pWhh1, unsigned short* __restrict__ pWih2,
                             unsigned short* __restrict__ pWhh2, unsigned short* __restrict__ pWdec,
                             float* __restrict__ bs1a, float* __restrict__ bs1b,
                             float* __restrict__ bs2, float* __restrict__ bdec) {
    const int bid = blockIdx.x;
    if (bid < 32) {
        pack_range(WC, pWC, bid * 256 + threadIdx.x, 2, 4, 256, 1024, 34);
    } else if (bid < 160) {
        pack_range(Wih1, pWih1, (bid - 32) * 256 + threadIdx.x, 8, 4, 256, 1024, 256);
    } else if (bid < 288) {
        pack_range(Whh1, pWhh1, (bid - 160) * 256 + threadIdx.x, 8, 4, 256, 1024, 256);
    } else if (bid < 416) {
        pack_range(Wih2, pWih2, (bid - 288) * 256 + threadIdx.x, 8, 4, 256, 1024, 256);
    } else if (bid < 544) {
        pack_range(Whh2, pWhh2, (bid - 416) * 256 + threadIdx.x, 8, 4, 256, 1024, 256);
    } else if (bid < 550) {
        int idx = (bid - 544) * 256 + threadIdx.x;
        if (idx < 1536) pack_range(W_dec, pWdec, idx, 8, 1, 0, 34, 256);
    } else {
        int j = (bid - 550) * 256 + threadIdx.x;
        if (j < 1024) {
            float s = bih1[j] + bhh1[j];
            bs1a[j] = s + benc[j];
            bs1b[j] = s;
            bs2[j] = bih2[j] + bhh2[j];
        }
        if (bid == 550 && threadIdx.x < 48)
            bdec[threadIdx.x] = (threadIdx.x < 34) ? b_dec[threadIdx.x] : 0.f;
    }
}

// ---------------- fused LSTM kernel (R8 verbatim — best verified: 675 us) ----------------
//
// A layout (frag-linear, conflict-free): block (u, mt) at
//   base + (u*4 + mt)*520 + lane*8  (shorts); element = Act[mt*16+(l&15)][u*32+(l>>4)*8+j].
//
// B streams GLOBAL -> REGISTERS (no LDS round-trip). b0/b1 double-buffer: tile v
// consumes buf (v&1), then reloads that buffer with W(v+2) -> one full tile of
// load cover. All loads register-dependent -> compiler inserts exact counted
// s_waitcnt. A single-buffered with per-mt after-use reload. h double-buffered
// in LDS -> h written inline per-s, ONE barrier per cell_step.
// DO NOT: unroll the tile-pair loop (R9: scheduler renames loads -> spill
// catastrophe) or extend b0/b1 live ranges across cells (R10: FETCH/WRITE x5).
// The #pragma unroll 1 is load-bearing — it bounds operand live ranges.

template<bool DO_A, bool DO_W>
__device__ __forceinline__ void tile_op(s16x8 (&a)[4], s16x8 (&bb)[4], f32x4 (&acc)[4][4],
                                        const unsigned short* aNext,
                                        const unsigned short* wNext, int lane) {
    #pragma unroll
    for (int mt = 0; mt < 4; ++mt) {
        acc[0][mt] = MFMA(a[mt], bb[0], acc[0][mt]);
        acc[1][mt] = MFMA(a[mt], bb[1], acc[1][mt]);
        acc[2][mt] = MFMA(a[mt], bb[2], acc[2][mt]);
        acc[3][mt] = MFMA(a[mt], bb[3], acc[3][mt]);
        if constexpr (DO_A) a[mt] = *(const s16x8*)(aNext + mt * 520 + lane * 8);
        SCHED0;
    }
    if constexpr (DO_W) {
        bb[0] = *(const s16x8*)(wNext + lane * 8);
        bb[1] = *(const s16x8*)(wNext + 512 + lane * 8);
        bb[2] = *(const s16x8*)(wNext + 1024 + lane * 8);
        bb[3] = *(const s16x8*)(wNext + 1536 + lane * 8);
    }
    SCHED0;
}

template<int KKIN>
__device__ __forceinline__ void cell_step(
    const unsigned short* Ain,   // frag-linear (tile u at +u*2080)
    const unsigned short* Ahid,
    const unsigned short* __restrict__ pWin,
    const unsigned short* __restrict__ pWhid,
    const float* Lbias, float (&cst)[2][4][4], unsigned short* Hout,
    int wave, int lane, int ln15, int quad) {
    constexpr int T = KKIN + 8;  // 10 or 16 (even)
    const int wv2 = wave * 2;

    auto bsrc = [&](int v) -> const unsigned short* {  // v in [0, 2T)
        int ss = (v >= T) ? 1 : 0;
        int u = v - ss * T;
        int ntb = wv2 + ss;
        return (u < KKIN) ? pWin + (ntb * KKIN + u) * 2048
                          : pWhid + (ntb * 8 + (u - KKIN)) * 2048;
    };
    auto asrc = [&](int v) -> const unsigned short* {
        int u = (v >= T) ? v - T : v;
        return (u < KKIN) ? Ain + u * 2080 : Ahid + (u - KKIN) * 2080;
    };

    s16x8 a[4], b0[4], b1[4];
    f32x4 acc[4][4];

    // prologue: W(0)->b0, W(1)->b1 in flight; a = A(0)
    {
        const unsigned short* p0 = bsrc(0);
        const unsigned short* p1 = bsrc(1);
        b0[0] = *(const s16x8*)(p0 + lane * 8);
        b0[1] = *(const s16x8*)(p0 + 512 + lane * 8);
        b0[2] = *(const s16x8*)(p0 + 1024 + lane * 8);
        b0[3] = *(const s16x8*)(p0 + 1536 + lane * 8);
        b1[0] = *(const s16x8*)(p1 + lane * 8);
        b1[1] = *(const s16x8*)(p1 + 512 + lane * 8);
        b1[2] = *(const s16x8*)(p1 + 1024 + lane * 8);
        b1[3] = *(const s16x8*)(p1 + 1536 + lane * 8);
        const unsigned short* ap = asrc(0);
        #pragma unroll
        for (int mt = 0; mt < 4; ++mt)
            a[mt] = *(const s16x8*)(ap + mt * 520 + lane * 8);
    }

    #pragma unroll
    for (int s = 0; s < 2; ++s) {
        #pragma unroll
        for (int g = 0; g < 4; ++g)
            #pragma unroll
            for (int mt = 0; mt < 4; ++mt) acc[g][mt] = f32x4{0.f, 0.f, 0.f, 0.f};
        const int base = s * T;
        const int nrm = s ? (T - 2) : T;  // s=1: last pair peeled (drain)
        #pragma unroll 1
        for (int u = 0; u < nrm; u += 2) {
            const int v = base + u;  // even
            tile_op<true, true>(a, b0, acc, asrc(v + 1), bsrc(v + 2), lane);
            tile_op<true, true>(a, b1, acc, asrc(v + 2), bsrc(v + 3), lane);
        }
        if (s == 1) {
            tile_op<true, false>(a, b0, acc, asrc(2 * T - 1), nullptr, lane);
            tile_op<false, false>(a, b1, acc, nullptr, nullptr, lane);
        }

        // epilogue for column-stream s: gates -> c,h; h written inline (Hout is
        // the parity buffer nobody reads this step).
        const int colB = (wv2 + s) * 16 + ln15;
        const float bi = Lbias[colB], bff = Lbias[256 + colB];
        const float bg = Lbias[512 + colB], bo = Lbias[768 + colB];
        #pragma unroll
        for (int mt = 0; mt < 4; ++mt) {
            #pragma unroll
            for (int r = 0; r < 4; ++r) {
                float iv = acc[0][mt][r] + bi;
                float fv = acc[1][mt][r] + bff;
                float gv = acc[2][mt][r] + bg;
                float ov = acc[3][mt][r] + bo;
                float cn = sigm(fv) * cst[s][mt][r] + sigm(iv) * tanh_(gv);
                cst[s][mt][r] = cn;
                float hv = sigm(ov) * tanh_(cn);
                // frag-linear scatter: row=mt*16+quad*4+r, col=colB
                Hout[(wave * 4 + mt) * 520 + (quad * 4 + r) * 8 +
                     (2 * s + (ln15 >> 3)) * 128 + (ln15 & 7)] = f2bf(hv);
            }
        }
    }
    __syncthreads();  // publish new h (single barrier per cell)
}

// LDS: h1f[2] + h2f[2] (4 x 33280) + scratch 12288 + Lb 12288 + Lbd 256 = 157952 B.
__global__ __launch_bounds__(512, 1) void lstm_fused(
    const float* __restrict__ x,
    const unsigned short* __restrict__ pWC,
    const unsigned short* __restrict__ pWih1,
    const unsigned short* __restrict__ pWhh1,
    const unsigned short* __restrict__ pWih2,
    const unsigned short* __restrict__ pWhh2,
    const unsigned short* __restrict__ pWdec,
    const float* __restrict__ gb1a, const float* __restrict__ gb1b,
    const float* __restrict__ gb2, const float* __restrict__ gbd,
    float* __restrict__ out) {
    extern __shared__ unsigned char smem[];
    unsigned short* h1lo = (unsigned short*)smem;                 // 16640 shorts each
    unsigned short* h1hi = h1lo + 16640;
    unsigned short* h2lo = h1hi + 16640;
    unsigned short* h2hi = h2lo + 16640;
    unsigned char* scratch = (unsigned char*)(h2hi + 16640);      // 12288 B union:
    unsigned short* xfrag = (unsigned short*)scratch;             //   obs: 2u x 4mt x 520
    float* dOut = (float*)scratch;                                //   dec: 64 x 48 f32
    float* Lb1a = (float*)(scratch + 12288);
    float* Lb1b = Lb1a + 1024;
    float* Lb2  = Lb1b + 1024;
    float* Lbd  = Lb2 + 1024;                                     // 48 used (256 B)

    const int tid = threadIdx.x;
    const int wave = tid >> 6;
    const int lane = tid & 63;
    const int ln15 = lane & 15;
    const int quad = lane >> 4;
    const int m0 = blockIdx.x * 64;

    for (int i = tid; i < 33280; i += 512) ((int*)h1lo)[i] = 0;   // all 4 h buffers
    for (int i = tid; i < 3072; i += 512) ((int*)scratch)[i] = 0;
    for (int i = tid; i < 1024; i += 512) { Lb1a[i] = gb1a[i]; Lb1b[i] = gb1b[i]; Lb2[i] = gb2[i]; }
    if (tid < 48) Lbd[tid] = gbd[tid];

    float c1[2][4][4], c2[2][4][4];
    #pragma unroll
    for (int s = 0; s < 2; ++s)
        #pragma unroll
        for (int mt = 0; mt < 4; ++mt)
            #pragma unroll
            for (int r = 0; r < 4; ++r) { c1[s][mt][r] = 0.f; c2[s][mt][r] = 0.f; }

    __syncthreads();

    #pragma unroll 1
    for (int t = 0; t < 19; ++t) {
        const int cur = t & 1;
        unsigned short* h1r = cur ? h1hi : h1lo;
        unsigned short* h1w = cur ? h1lo : h1hi;
        unsigned short* h2r = cur ? h2hi : h2lo;
        unsigned short* h2w = cur ? h2lo : h2hi;

        if (t < 10) {
            // stage x_t -> xfrag (bf16, fragment-linear; chunks for cols 34..63 stay zero)
            for (int i = tid; i < 1088; i += 512) {
                int r = i / 17, p = i - r * 17;
                int c = 2 * p;
                f32x2 v = __builtin_nontemporal_load((const f32x2*)(x + (m0 + r) * 340 + t * 34) + p);
                int u = c >> 5, mt = r >> 4;
                int laneA = (r & 15) | (((c >> 3) & 3) << 4);
                unsigned int packed = (unsigned int)f2bf(v.x) | ((unsigned int)f2bf(v.y) << 16);
                *(unsigned int*)(xfrag + (u * 4 + mt) * 520 + laneA * 8 + (c & 7)) = packed;
            }
            __syncthreads();
            cell_step<2>(xfrag, h1r, pWC, pWhh1, Lb1a, c1, h1w, wave, lane, ln15, quad);
        } else {
            cell_step<8>(h2r, h1r, pWih1, pWhh1, Lb1b, c1, h1w, wave, lane, ln15, quad);
        }
        cell_step<8>(h1w, h2r, pWih2, pWhh2, Lb2, c2, h2w, wave, lane, ln15, quad);

        if (t >= 9) {
            const int tout = t - 9;
            if (wave < 3) {  // decoder: dec = h2 @ W_dec^T + b_dec ; cumsum in dOut (LDS)
                f32x4 d[4];
                #pragma unroll
                for (int mt = 0; mt < 4; ++mt) d[mt] = f32x4{0.f, 0.f, 0.f, 0.f};
                const unsigned short* hb = h2w + lane * 8;
                const unsigned short* wb = pWdec + (wave * 8) * 512 + lane * 8;
                #pragma unroll
                for (int kk = 0; kk < 8; ++kk) {
                    s16x8 b = *(const s16x8*)(wb + kk * 512);
                    #pragma unroll
                    for (int mt = 0; mt < 4; ++mt) {
                        s16x8 a = *(const s16x8*)(hb + (kk * 4 + mt) * 520);
                        d[mt] = MFMA(a, b, d[mt]);
                    }
                }
                const int col = wave * 16 + ln15;
                const bool valid = (col < 34);
                const float bd = Lbd[col];
                #pragma unroll
                for (int mt = 0; mt < 4; ++mt) {
                    #pragma unroll
                    for (int r = 0; r < 4; ++r) {
                        const int rloc = mt * 16 + quad * 4 + r;
                        float v = d[mt][r] + bd;
                        if (tout == 0) {
                            float xr = valid ? __builtin_nontemporal_load(x + (m0 + rloc) * 340 + 306 + col) : 0.f;
                            dOut[rloc * 48 + col] = v + xr;
                        } else {
                            dOut[rloc * 48 + col] += v;
                        }
                    }
                }
            }
            __syncthreads();
            // contiguous per-row non-temporal stores
            for (int i = tid; i < 1088; i += 512) {
                int r = i / 17, p = i - r * 17;
                f32x2 v = *(const f32x2*)(dOut + r * 48 + p * 2);
                __builtin_nontemporal_store(v, (f32x2*)(out + (m0 + r) * 340 + tout * 34) + p);
            }
            // safe: staging only at t<10, decoder rewrite of dOut only after 2 cell barriers
        }
    }
}

// ---------------- launch ----------------

extern "C" void kernel_launch(void* const* d_in, const int* in_sizes, int n_in,
                              void* d_out, int out_size, void* d_ws, size_t ws_size,
                              hipStream_t stream) {
    const float* x     = (const float*)d_in[0];
    const float* W_enc = (const float*)d_in[1];
    const float* b_enc = (const float*)d_in[2];
    const float* Wih1  = (const float*)d_in[3];
    const float* Whh1  = (const float*)d_in[4];
    const float* bih1  = (const float*)d_in[5];
    const float* bhh1  = (const float*)d_in[6];
    const float* Wih2  = (const float*)d_in[7];
    const float* Whh2  = (const float*)d_in[8];
    const float* bih2  = (const float*)d_in[9];
    const float* bhh2  = (const float*)d_in[10];
    const float* W_dec = (const float*)d_in[11];
    const float* b_dec = (const float*)d_in[12];
    float* out = (float*)d_out;

    unsigned char* w = (unsigned char*)d_ws;
    float* WC   = (float*)(w + 0);         // 139264
    float* benc = (float*)(w + 139264);    // 4096
    float* bs1a = (float*)(w + 143360);
    float* bs1b = (float*)(w + 147456);
    float* bs2  = (float*)(w + 151552);
    float* bdec = (float*)(w + 155648);    // 256
    unsigned short* pWC   = (unsigned short*)(w + 155904);   // 131072
    unsigned short* pWih1 = (unsigned short*)(w + 286976);   // 524288 each
    unsigned short* pWhh1 = (unsigned short*)(w + 811264);
    unsigned short* pWih2 = (unsigned short*)(w + 1335552);
    unsigned short* pWhh2 = (unsigned short*)(w + 1859840);
    unsigned short* pWdec = (unsigned short*)(w + 2384128);  // 24576

    wc_kernel<<<140, 256, 0, stream>>>(Wih1, W_enc, b_enc, WC, benc);
    prep2_kernel<<<554, 256, 0, stream>>>(WC, benc, Wih1, Whh1, Wih2, Whh2, W_dec,
                                          bih1, bhh1, bih2, bhh2, b_dec,
                                          pWC, pWih1, pWhh1, pWih2, pWhh2, pWdec,
                                          bs1a, bs1b, bs2, bdec);

    hipFuncSetAttribute((const void*)lstm_fused, hipFuncAttributeMaxDynamicSharedMemorySize, 157952);
    lstm_fused<<<256, 512, 157952, stream>>>(x, pWC, pWih1, pWhh1, pWih2, pWhh2, pWdec,
                                             bs1a, bs1b, bs2, bdec, out);
}